// Round 13
// baseline (123.295 us; speedup 1.0000x reference)
//
#include <hip/hip_runtime.h>
#include <stdint.h>

namespace {

constexpr int   B_   = 64;
constexpr int   F0_  = 1876;
constexpr int   F1_  = 1024;
constexpr int   F2_  = 10;
constexpr int   NT_  = 151;
constexpr float DT_  = 0.02f;
constexpr float SCL_  = 1073741824.0f;      // 2^30 fixed-point scale
constexpr float ISCL_ = 1.0f / 1073741824.0f;

constexpr int NBLK_W = (F1_ * F0_) / 256;   // 7504 (exact)
constexpr int NBLK_R = 469;                  // ceil(64*1876/256) = 469 (exact)

// workspace layout (bytes)
constexpr size_t OFF_W1I  = 0;                     // 1876*1024*4 = 7,684,096
constexpr size_t OFF_REC  = 7684096;               // 64*1876*8   =   960,512
constexpr size_t OFF_IDX1 = OFF_REC + 960512;      // 64*1024 u8  =    65,536

// ---------------------------------------------------------------------------
// k_prep: (a) blocks < 7504: W1i[n] = rn(W1[n] * 2^30)   (same j-major layout,
//             hoists the per-(j,i) scale+round out of the 64x-replayed loop)
//         (b) blocks >= 7504: rec[b*1876+i] = { k*8, ti_bits },
//             k = min(ceil(ti*50), 50)  (hoists per-(b,i) bin computation).
// ---------------------------------------------------------------------------
__global__ __launch_bounds__(256) void k_prep(const float* __restrict__ W1,
                                              const float* __restrict__ ti,
                                              int* __restrict__ W1i,
                                              uint2* __restrict__ rec) {
  if (blockIdx.x < NBLK_W) {
    int n = blockIdx.x * 256 + threadIdx.x;      // < 1,921,024
    W1i[n] = __float2int_rn(W1[n] * SCL_);
  } else {
    int n = (blockIdx.x - NBLK_W) * 256 + threadIdx.x;
    if (n < B_ * F0_) {
      float v = ti[n];
      int k = (int)fminf(ceilf(v * 50.0f), 50.0f);   // ti >= 0 -> k >= 0
      rec[n] = make_uint2((uint32_t)k * 8u, __float_as_uint(v));
    }
  }
}

// ---------------------------------------------------------------------------
// Layer 1: 4096 blocks = b*64 + jg (XCD = jg%8 -> ~1 MB W1i slice L2-fit),
// 1024 threads = 16 waves; wave wv owns j = jg*16+wv; lane streams i.
// All loads induction-addressed & coalesced (r12-proven structure).
// Per element ONE packed ds_add_u64 into bins[copy=lane>>3][wv][k]:
//   packed = (a<<32) | (c mod 2^32),  a = rn(w*2^30), c = rn(f32(a)*ti).
// Modular identity: sum(packed) == (sum a)<<32 + (sum c) (mod 2^64); with
// |sums| < 2^31 both recover exactly -> bit-deterministic (int adds commute).
// 8 copies cut same-bin collisions (r12: 21M conflict cycles at 4 copies).
// Phase 2: collapse copies, unpack, 64-lane shfl_up scan, 3-ballot crossing.
// ---------------------------------------------------------------------------
__global__ __launch_bounds__(1024, 8) void k_main1(const uint2* __restrict__ rec,
                                                   const int* __restrict__ W1i,
                                                   uint8_t* __restrict__ idx1) {
  __shared__ unsigned long long bins[8][16][52];   // 53,248 B
  const int blk  = blockIdx.x;        // 4096
  const int b    = blk >> 6;
  const int jg   = blk & 63;
  const int tid  = threadIdx.x;
  const int lane = tid & 63;
  const int wv   = tid >> 6;          // j_local 0..15

  {
    int4* p = (int4*)(&bins[0][0][0]);
    for (int s = tid; s < (int)(sizeof(bins) / 16); s += 1024)
      p[s] = make_int4(0, 0, 0, 0);
  }
  __syncthreads();

  const int j = (jg << 4) + wv;
  const int*  __restrict__ wrow = W1i + (size_t)j * F0_;
  const uint2* __restrict__ rb  = rec + (size_t)b * F0_;
  char* const cell0 = (char*)(&bins[lane >> 3][wv][0]);

#define ELEM(i) {                                                             \
    int   a  = wrow[i];                       /* coalesced, L2-resident */    \
    uint2 r  = rb[i];                         /* coalesced, L1-shared   */    \
    float tv = __uint_as_float(r.y);                                          \
    int   c  = __float2int_rn((float)a * tv);                                 \
    unsigned long long pk =                                                   \
        ((unsigned long long)(unsigned)a << 32) | (unsigned)c;                \
    atomicAdd((unsigned long long*)(cell0 + r.x), pk); }

#pragma unroll 4
  for (int it = 0; it < 29; ++it) {           // i = 0 .. 1855
    const int i = (it << 6) + lane;
    ELEM(i);
  }
  {                                           // tail i = 1856 .. 1875
    const int i = 1856 + lane;
    if (i < F0_) ELEM(i);
  }
#undef ELEM
  __syncthreads();

  // phase 2: per wave (own j). lane<51 holds bin 'lane'; inclusive shfl scan
  // gives SA(t=lane), SC(t=lane); lanes >=51 carry the totals.
  float sa = 0.f, sc = 0.f;
  if (lane < 51) {
    unsigned long long s = 0ull;
#pragma unroll
    for (int cp = 0; cp < 8; ++cp) s += bins[cp][wv][lane];
    int cl = (int)(unsigned)(s & 0xFFFFFFFFull);
    int ah = (int)(unsigned)(s >> 32);
    if (cl < 0) ah += 1;                      // borrow correction (exact)
    sa = (float)ah * ISCL_;
    sc = (float)cl * ISCL_;
  }
#pragma unroll
  for (int d = 1; d < 64; d <<= 1) {
    float s2 = __shfl_up(sa, d);
    float c2 = __shfl_up(sc, d);
    if (lane >= d) { sa += s2; sc += c2; }
  }
  const float saT = __shfl(sa, 63);           // totals (lanes 51..63 add 0)
  const float scT = __shfl(sc, 63);
  float m0 = (float)lane * DT_ * sa - sc;             // t = lane
  float m1 = (float)(lane + 64) * DT_ * saT - scT;    // t = lane+64
  float m2 = (float)(lane + 128) * DT_ * saT - scT;   // t = lane+128
  unsigned long long b0 = __ballot(m0 >= 1.0f);
  unsigned long long b1 = __ballot(m1 >= 1.0f);
  unsigned long long b2 = __ballot(m2 >= 1.0f);
  b2 &= (1ull << 23) - 1;                     // t <= 150
  b2 |= (1ull << 22);                         // forced spike at t = 150
  int idx;
  if (b0)      idx = __ffsll((long long)b0) - 1;
  else if (b1) idx = 64 + __ffsll((long long)b1) - 1;
  else         idx = 128 + __ffsll((long long)b2) - 1;
  if (lane == 0) idx1[((size_t)b << 10) + j] = (uint8_t)idx;
}

// ---------------------------------------------------------------------------
// Layer-2: brute force. Block = (b,j), 4 waves split the i-range; lane = t.
// (unchanged, proven)
// ---------------------------------------------------------------------------
__global__ __launch_bounds__(256) void k_main2(const uint8_t* __restrict__ idx1,
                                               const float* __restrict__ W2,
                                               float* __restrict__ out) {
  __shared__ float wrow[F1_];
  __shared__ float tirow[F1_];
  __shared__ float part[4][3][64];
  const int blk = blockIdx.x;          // 640
  const int b   = blk / 10;
  const int j   = blk - b * 10;
  const int tid = threadIdx.x;
  const int lane = tid & 63, wvv = tid >> 6;

  const float*   w = W2  + (size_t)j * F1_;
  const uint8_t* h = idx1 + (size_t)b * F1_;
  for (int s = tid; s < F1_; s += 256) {
    wrow[s]  = w[s];
    tirow[s] = (float)h[s] * DT_;
  }
  __syncthreads();

  const float tl0 = (float)lane * DT_;
  const float tl1 = (float)(lane + 64) * DT_;
  const float tl2 = (float)(lane + 128) * DT_;
  float m0 = 0.f, m1 = 0.f, m2 = 0.f;
  const int i0 = wvv * 256;
#pragma unroll 4
  for (int i = i0; i < i0 + 256; ++i) {
    float tiv = tirow[i], ww = wrow[i];
    m0 = fmaf(ww, fmaxf(tl0 - tiv, 0.f), m0);
    m1 = fmaf(ww, fmaxf(tl1 - tiv, 0.f), m1);
    m2 = fmaf(ww, fmaxf(tl2 - tiv, 0.f), m2);
  }
  part[wvv][0][lane] = m0;
  part[wvv][1][lane] = m1;
  part[wvv][2][lane] = m2;
  __syncthreads();

  if (wvv == 0) {
    m0 = part[0][0][lane] + part[1][0][lane] + part[2][0][lane] + part[3][0][lane];
    m1 = part[0][1][lane] + part[1][1][lane] + part[2][1][lane] + part[3][1][lane];
    m2 = part[0][2][lane] + part[1][2][lane] + part[2][2][lane] + part[3][2][lane];
    unsigned long long b0 = __ballot(m0 >= 1.0f);
    unsigned long long b1 = __ballot(m1 >= 1.0f);
    unsigned long long b2 = __ballot(m2 >= 1.0f);
    b2 &= (1ull << 23) - 1;            // t <= 150
    b2 |= (1ull << 22);                // forced spike at t = 150
    int tres;
    if (b0)      tres = __ffsll((long long)b0) - 1;
    else if (b1) tres = 64 + __ffsll((long long)b1) - 1;
    else         tres = 128 + __ffsll((long long)b2) - 1;
    if (lane == 0) out[(size_t)b * F2_ + j] = (float)tres * DT_;
  }
}

}  // namespace

// ---------------------------------------------------------------------------
extern "C" void kernel_launch(void* const* d_in, const int* in_sizes, int n_in,
                              void* d_out, int out_size, void* d_ws, size_t ws_size,
                              hipStream_t stream) {
  const float* ti = (const float*)d_in[0];   // [64][1876]
  const float* W1 = (const float*)d_in[1];   // [1024][1876]
  const float* W2 = (const float*)d_in[2];   // [10][1024]
  float* out = (float*)d_out;                // [64][10]

  char* ws = (char*)d_ws;
  int*     W1i  = (int*)(ws + OFF_W1I);
  uint2*   rec  = (uint2*)(ws + OFF_REC);
  uint8_t* idx1 = (uint8_t*)(ws + OFF_IDX1);

  hipLaunchKernelGGL(k_prep,  dim3(NBLK_W + NBLK_R), dim3(256), 0, stream,
                     W1, ti, W1i, rec);
  hipLaunchKernelGGL(k_main1, dim3(4096), dim3(1024), 0, stream, rec, W1i, idx1);
  hipLaunchKernelGGL(k_main2, dim3(640),  dim3(256),  0, stream, idx1, W2, out);
}

// Round 14
// 123.035 us; speedup vs baseline: 1.0021x; 1.0021x over previous
//
#include <hip/hip_runtime.h>
#include <stdint.h>

namespace {

constexpr int   B_   = 64;
constexpr int   F0_  = 1876;
constexpr int   F1_  = 1024;
constexpr int   F2_  = 10;
constexpr int   NT_  = 151;
constexpr float DT_  = 0.02f;
constexpr float SCL_  = 1073741824.0f;      // 2^30 fixed-point scale
constexpr float ISCL_ = 1.0f / 1073741824.0f;

constexpr int NBLK_W = (F1_ * F0_) / 256;   // 7504 (exact)
constexpr int NBLK_R = 469;                  // 64*1876/256 = 469 (exact)

// workspace layout (bytes)
constexpr size_t OFF_W1I  = 0;                     // 1876*1024*4 = 7,684,096
constexpr size_t OFF_REC  = 7684096;               // 64*1876*8   =   960,512
constexpr size_t OFF_IDX1 = OFF_REC + 960512;      // 64*1024 u8  =    65,536

// ---------------------------------------------------------------------------
// k_prep: (a) blocks < 7504: W1i[n] = rn(W1[n] * 2^30)  (j-major layout)
//         (b) blocks >= 7504: rec[b*1876+i] = { k*8, ti_bits },
//             k = min(ceil(ti*50), 50).
// ---------------------------------------------------------------------------
__global__ __launch_bounds__(256) void k_prep(const float* __restrict__ W1,
                                              const float* __restrict__ ti,
                                              int* __restrict__ W1i,
                                              uint2* __restrict__ rec) {
  if (blockIdx.x < NBLK_W) {
    int n = blockIdx.x * 256 + threadIdx.x;
    W1i[n] = __float2int_rn(W1[n] * SCL_);
  } else {
    int n = (blockIdx.x - NBLK_W) * 256 + threadIdx.x;
    if (n < B_ * F0_) {
      float v = ti[n];
      int k = (int)fminf(ceilf(v * 50.0f), 50.0f);   // ti >= 0 -> k >= 0
      rec[n] = make_uint2((uint32_t)k * 8u, __float_as_uint(v));
    }
  }
}

// ---------------------------------------------------------------------------
// Layer 1 (r13 structure + BANK-SKEWED bins): 4096 blocks = b*64 + jg
// (XCD = jg%8 -> ~1.9 MB/XCD working set, L2-fit), 1024 threads = 16 waves;
// wave wv owns j = jg*16+wv; lane streams i; all loads induction-addressed.
// bins[wv][cp][53]: copy stride 53 words == 5 (mod 16 bank-pairs) -> the 8
// copies of bin k hit 8 DISTINCT bank-pairs (r12/r13 had stride == 0 mod 32
// banks: all copies aliased -> 16-21M conflict cycles, the dominant stall).
// Per element ONE packed ds_add_u64: pk = (a<<32)|(c mod 2^32), a=rn(w*2^30),
// c=rn(f32(a)*ti); modular sums recover exactly up to a deterministic
// ~N_neg*2^-30 (~2e-8) residual (r13: absmax 0.0).  Int adds commute ->
// bit-deterministic.  Phase 2: collapse copies, unpack, shfl_up scan,
// 3-ballot first-crossing.
// ---------------------------------------------------------------------------
__global__ __launch_bounds__(1024, 8) void k_main1(const uint2* __restrict__ rec,
                                                   const int* __restrict__ W1i,
                                                   uint8_t* __restrict__ idx1) {
  __shared__ unsigned long long bins[16][8][53];   // 54,272 B
  const int blk  = blockIdx.x;        // 4096
  const int b    = blk >> 6;
  const int jg   = blk & 63;
  const int tid  = threadIdx.x;
  const int lane = tid & 63;
  const int wv   = tid >> 6;          // j_local 0..15

  {
    int4* p = (int4*)(&bins[0][0][0]);
    for (int s = tid; s < (int)(sizeof(bins) / 16); s += 1024)
      p[s] = make_int4(0, 0, 0, 0);
  }
  __syncthreads();

  const int j = (jg << 4) + wv;
  const int*   __restrict__ wrow = W1i + (size_t)j * F0_;
  const uint2* __restrict__ rb   = rec + (size_t)b * F0_;
  char* const cell0 = (char*)(&bins[wv][lane >> 3][0]);

#define ELEM(i) {                                                             \
    int   a  = wrow[i];                       /* coalesced, L2-resident */    \
    uint2 r  = rb[i];                         /* coalesced, L1-shared   */    \
    float tv = __uint_as_float(r.y);                                          \
    int   c  = __float2int_rn((float)a * tv);                                 \
    unsigned long long pk =                                                   \
        ((unsigned long long)(unsigned)a << 32) | (unsigned)c;                \
    atomicAdd((unsigned long long*)(cell0 + r.x), pk); }

#pragma unroll 4
  for (int it = 0; it < 29; ++it) {           // i = 0 .. 1855
    const int i = (it << 6) + lane;
    ELEM(i);
  }
  {                                           // tail i = 1856 .. 1875
    const int i = 1856 + lane;
    if (i < F0_) ELEM(i);
  }
#undef ELEM
  __syncthreads();

  // phase 2: per wave (own j). lane<51 holds bin 'lane'; inclusive shfl scan
  // gives SA(t=lane), SC(t=lane); lanes >=51 carry the totals.
  float sa = 0.f, sc = 0.f;
  if (lane < 51) {
    unsigned long long s = 0ull;
#pragma unroll
    for (int cp = 0; cp < 8; ++cp) s += bins[wv][cp][lane];
    int cl = (int)(unsigned)(s & 0xFFFFFFFFull);
    int ah = (int)(unsigned)(s >> 32);
    if (cl < 0) ah += 1;                      // borrow correction
    sa = (float)ah * ISCL_;
    sc = (float)cl * ISCL_;
  }
#pragma unroll
  for (int d = 1; d < 64; d <<= 1) {
    float s2 = __shfl_up(sa, d);
    float c2 = __shfl_up(sc, d);
    if (lane >= d) { sa += s2; sc += c2; }
  }
  const float saT = __shfl(sa, 63);           // totals (lanes 51..63 add 0)
  const float scT = __shfl(sc, 63);
  float m0 = (float)lane * DT_ * sa - sc;             // t = lane
  float m1 = (float)(lane + 64) * DT_ * saT - scT;    // t = lane+64
  float m2 = (float)(lane + 128) * DT_ * saT - scT;   // t = lane+128
  unsigned long long b0 = __ballot(m0 >= 1.0f);
  unsigned long long b1 = __ballot(m1 >= 1.0f);
  unsigned long long b2 = __ballot(m2 >= 1.0f);
  b2 &= (1ull << 23) - 1;                     // t <= 150
  b2 |= (1ull << 22);                         // forced spike at t = 150
  int idx;
  if (b0)      idx = __ffsll((long long)b0) - 1;
  else if (b1) idx = 64 + __ffsll((long long)b1) - 1;
  else         idx = 128 + __ffsll((long long)b2) - 1;
  if (lane == 0) idx1[((size_t)b << 10) + j] = (uint8_t)idx;
}

// ---------------------------------------------------------------------------
// Layer-2: brute force. Block = (b,j), 4 waves split the i-range; lane = t.
// (unchanged, proven)
// ---------------------------------------------------------------------------
__global__ __launch_bounds__(256) void k_main2(const uint8_t* __restrict__ idx1,
                                               const float* __restrict__ W2,
                                               float* __restrict__ out) {
  __shared__ float wrow[F1_];
  __shared__ float tirow[F1_];
  __shared__ float part[4][3][64];
  const int blk = blockIdx.x;          // 640
  const int b   = blk / 10;
  const int j   = blk - b * 10;
  const int tid = threadIdx.x;
  const int lane = tid & 63, wvv = tid >> 6;

  const float*   w = W2  + (size_t)j * F1_;
  const uint8_t* h = idx1 + (size_t)b * F1_;
  for (int s = tid; s < F1_; s += 256) {
    wrow[s]  = w[s];
    tirow[s] = (float)h[s] * DT_;
  }
  __syncthreads();

  const float tl0 = (float)lane * DT_;
  const float tl1 = (float)(lane + 64) * DT_;
  const float tl2 = (float)(lane + 128) * DT_;
  float m0 = 0.f, m1 = 0.f, m2 = 0.f;
  const int i0 = wvv * 256;
#pragma unroll 4
  for (int i = i0; i < i0 + 256; ++i) {
    float tiv = tirow[i], ww = wrow[i];
    m0 = fmaf(ww, fmaxf(tl0 - tiv, 0.f), m0);
    m1 = fmaf(ww, fmaxf(tl1 - tiv, 0.f), m1);
    m2 = fmaf(ww, fmaxf(tl2 - tiv, 0.f), m2);
  }
  part[wvv][0][lane] = m0;
  part[wvv][1][lane] = m1;
  part[wvv][2][lane] = m2;
  __syncthreads();

  if (wvv == 0) {
    m0 = part[0][0][lane] + part[1][0][lane] + part[2][0][lane] + part[3][0][lane];
    m1 = part[0][1][lane] + part[1][1][lane] + part[2][1][lane] + part[3][1][lane];
    m2 = part[0][2][lane] + part[1][2][lane] + part[2][2][lane] + part[3][2][lane];
    unsigned long long b0 = __ballot(m0 >= 1.0f);
    unsigned long long b1 = __ballot(m1 >= 1.0f);
    unsigned long long b2 = __ballot(m2 >= 1.0f);
    b2 &= (1ull << 23) - 1;            // t <= 150
    b2 |= (1ull << 22);                // forced spike at t = 150
    int tres;
    if (b0)      tres = __ffsll((long long)b0) - 1;
    else if (b1) tres = 64 + __ffsll((long long)b1) - 1;
    else         tres = 128 + __ffsll((long long)b2) - 1;
    if (lane == 0) out[(size_t)b * F2_ + j] = (float)tres * DT_;
  }
}

}  // namespace

// ---------------------------------------------------------------------------
extern "C" void kernel_launch(void* const* d_in, const int* in_sizes, int n_in,
                              void* d_out, int out_size, void* d_ws, size_t ws_size,
                              hipStream_t stream) {
  const float* ti = (const float*)d_in[0];   // [64][1876]
  const float* W1 = (const float*)d_in[1];   // [1024][1876]
  const float* W2 = (const float*)d_in[2];   // [10][1024]
  float* out = (float*)d_out;                // [64][10]

  char* ws = (char*)d_ws;
  int*     W1i  = (int*)(ws + OFF_W1I);
  uint2*   rec  = (uint2*)(ws + OFF_REC);
  uint8_t* idx1 = (uint8_t*)(ws + OFF_IDX1);

  hipLaunchKernelGGL(k_prep,  dim3(NBLK_W + NBLK_R), dim3(256), 0, stream,
                     W1, ti, W1i, rec);
  hipLaunchKernelGGL(k_main1, dim3(4096), dim3(1024), 0, stream, rec, W1i, idx1);
  hipLaunchKernelGGL(k_main2, dim3(640),  dim3(256),  0, stream, idx1, W2, out);
}